// Round 1
// baseline (19739.958 us; speedup 1.0000x reference)
//
#include <hip/hip_runtime.h>
#include <math.h>

#define TPB 256

static constexpr int CDIM = 512;
static constexpr int BATCH = 2;
static constexpr int HWD = 2304;   // HW == M (compress ratio 1)
static constexpr int GS = 9;       // group size (2304/256)
static constexpr long SZ = (long)BATCH * CDIM * HWD;   // 2,359,296 floats
static constexpr long SBIG = (long)BATCH * HWD * HWD;  // 10,616,832 floats
static constexpr float ALPHA = 0.05f;
static constexpr float TOLF = 4.608e-4f;               // B*HW*1e-7

__device__ __forceinline__ bool fista_done(const float* __restrict__ diffArr, int iter) {
    bool done = false;
    for (int j = 0; j < iter; ++j) done = done || (diffArr[j] <= TOLF);
    return done;
}

#define FMA16()                                                                              \
    acc[0][0] += ra.x * rb.x; acc[0][1] += ra.x * rb.y; acc[0][2] += ra.x * rb.z; acc[0][3] += ra.x * rb.w; \
    acc[1][0] += ra.y * rb.x; acc[1][1] += ra.y * rb.y; acc[1][2] += ra.y * rb.z; acc[1][3] += ra.y * rb.w; \
    acc[2][0] += ra.z * rb.x; acc[2][1] += ra.z * rb.y; acc[2][2] += ra.z * rb.z; acc[2][3] += ra.z * rb.w; \
    acc[3][0] += ra.w * rb.x; acc[3][1] += ra.w * rb.y; acc[3][2] += ra.w * rb.z; acc[3][3] += ra.w * rb.w;

// Generic f32 GEMM, 64x64x16 tile, 256 threads, 4x4 per thread.
// C[m,n] = sum_k A(m,k)*B(k,n); strides runtime; exactly one of {a_sm,a_sk} is 1, same for B.
// MODE: 0 = plain, 1 = +bias[m], 2 = resid (acc - Xsub, with FISTA early-out)
template<int MODE>
__global__ __launch_bounds__(TPB) void gemm_f32(
    const float* __restrict__ A, long a_bs, int a_sm, int a_sk,
    const float* __restrict__ B, long b_bs, int b_sk, int b_sn,
    float* __restrict__ C, long c_bs, int c_sm, int c_sn,
    int K,
    const float* __restrict__ bias,
    const float* __restrict__ Xsub,
    const float* __restrict__ diffArr, int iter)
{
    if (MODE == 2) {
        if (iter > 0 && fista_done(diffArr, iter)) return;
    }
    __shared__ float As[16][68];
    __shared__ float Bs[16][68];
    const int tid = threadIdx.x;
    const int tx = tid & 15, ty = tid >> 4;
    const int m0 = blockIdx.y << 6;
    const int n0 = blockIdx.x << 6;
    const float* Ab = A + (long)blockIdx.z * a_bs;
    const float* Bb = B + (long)blockIdx.z * b_bs;

    float acc[4][4] = {};

    for (int k0 = 0; k0 < K; k0 += 16) {
        if (a_sk == 1) {
            const int m = tid >> 2, kk = (tid & 3) << 2;
            const float4 v = *(const float4*)(Ab + (long)(m0 + m) * a_sm + (k0 + kk));
            As[kk + 0][m] = v.x; As[kk + 1][m] = v.y; As[kk + 2][m] = v.z; As[kk + 3][m] = v.w;
        } else { // a_sm == 1
            const int kk = tid >> 4, mm = (tid & 15) << 2;
            *(float4*)&As[kk][mm] = *(const float4*)(Ab + (long)(k0 + kk) * a_sk + (m0 + mm));
        }
        if (b_sk == 1) {
            const int n = tid >> 2, kk = (tid & 3) << 2;
            const float4 v = *(const float4*)(Bb + (long)(n0 + n) * b_sn + (k0 + kk));
            Bs[kk + 0][n] = v.x; Bs[kk + 1][n] = v.y; Bs[kk + 2][n] = v.z; Bs[kk + 3][n] = v.w;
        } else { // b_sn == 1
            const int kk = tid >> 4, nn = (tid & 15) << 2;
            *(float4*)&Bs[kk][nn] = *(const float4*)(Bb + (long)(k0 + kk) * b_sk + (n0 + nn));
        }
        __syncthreads();
        #pragma unroll
        for (int k = 0; k < 16; ++k) {
            const float4 ra = *(const float4*)&As[k][ty << 2];
            const float4 rb = *(const float4*)&Bs[k][tx << 2];
            FMA16();
        }
        __syncthreads();
    }

    float* Cb = C + (long)blockIdx.z * c_bs;
    const int mg = m0 + (ty << 2), ng = n0 + (tx << 2);
    #pragma unroll
    for (int i = 0; i < 4; ++i) {
        #pragma unroll
        for (int j = 0; j < 4; ++j) {
            const long off = (long)(mg + i) * c_sm + (long)(ng + j) * c_sn;
            float v = acc[i][j];
            if (MODE == 1) v += bias[mg + i];
            if (MODE == 2) v -= Xsub[off];
            Cb[off] = v;
        }
    }
}

// mean = S @ H^T, meansq = S @ (H^2)^T, epilogue -> mean/std written transposed [b][c][q]
__global__ __launch_bounds__(TPB) void gemm_meanstd(
    const float* __restrict__ S, const float* __restrict__ H,
    float* __restrict__ meanO, float* __restrict__ stdO)
{
    __shared__ float As[16][68];
    __shared__ float Bs[16][68];
    const int tid = threadIdx.x;
    const int tx = tid & 15, ty = tid >> 4;
    const int b = blockIdx.z;
    const int q0 = blockIdx.y << 6;   // M = HW (q)
    const int c0 = blockIdx.x << 6;   // N = C (c)
    const float* Sb = S + (long)b * HWD * HWD;
    const float* Hb = H + (long)b * CDIM * HWD;
    float a1[4][4] = {}, a2[4][4] = {};

    for (int k0 = 0; k0 < HWD; k0 += 16) {
        {
            const int m = tid >> 2, kk = (tid & 3) << 2;
            const float4 v = *(const float4*)(Sb + (long)(q0 + m) * HWD + (k0 + kk));
            As[kk + 0][m] = v.x; As[kk + 1][m] = v.y; As[kk + 2][m] = v.z; As[kk + 3][m] = v.w;
        }
        {
            const int n = tid >> 2, kk = (tid & 3) << 2;
            const float4 v = *(const float4*)(Hb + (long)(c0 + n) * HWD + (k0 + kk));
            Bs[kk + 0][n] = v.x; Bs[kk + 1][n] = v.y; Bs[kk + 2][n] = v.z; Bs[kk + 3][n] = v.w;
        }
        __syncthreads();
        #pragma unroll
        for (int k = 0; k < 16; ++k) {
            const float4 ra = *(const float4*)&As[k][ty << 2];
            const float4 rb = *(const float4*)&Bs[k][tx << 2];
            float4 rb2; rb2.x = rb.x * rb.x; rb2.y = rb.y * rb.y; rb2.z = rb.z * rb.z; rb2.w = rb.w * rb.w;
            a1[0][0] += ra.x * rb.x; a1[0][1] += ra.x * rb.y; a1[0][2] += ra.x * rb.z; a1[0][3] += ra.x * rb.w;
            a1[1][0] += ra.y * rb.x; a1[1][1] += ra.y * rb.y; a1[1][2] += ra.y * rb.z; a1[1][3] += ra.y * rb.w;
            a1[2][0] += ra.z * rb.x; a1[2][1] += ra.z * rb.y; a1[2][2] += ra.z * rb.z; a1[2][3] += ra.z * rb.w;
            a1[3][0] += ra.w * rb.x; a1[3][1] += ra.w * rb.y; a1[3][2] += ra.w * rb.z; a1[3][3] += ra.w * rb.w;
            a2[0][0] += ra.x * rb2.x; a2[0][1] += ra.x * rb2.y; a2[0][2] += ra.x * rb2.z; a2[0][3] += ra.x * rb2.w;
            a2[1][0] += ra.y * rb2.x; a2[1][1] += ra.y * rb2.y; a2[1][2] += ra.y * rb2.z; a2[1][3] += ra.y * rb2.w;
            a2[2][0] += ra.z * rb2.x; a2[2][1] += ra.z * rb2.y; a2[2][2] += ra.z * rb2.z; a2[2][3] += ra.z * rb2.w;
            a2[3][0] += ra.w * rb2.x; a2[3][1] += ra.w * rb2.y; a2[3][2] += ra.w * rb2.z; a2[3][3] += ra.w * rb2.w;
        }
        __syncthreads();
    }
    #pragma unroll
    for (int i = 0; i < 4; ++i) {
        #pragma unroll
        for (int j = 0; j < 4; ++j) {
            const int q = q0 + (ty << 2) + i;
            const int c = c0 + (tx << 2) + j;
            const long o = (long)b * CDIM * HWD + (long)c * HWD + q;
            const float m_ = a1[i][j];
            float v = a2[i][j] - m_ * m_;
            meanO[o] = m_;
            stdO[o] = sqrtf(v > 0.f ? v : 0.f);
        }
    }
}

// grad = resid @ A (NN), fused FISTA update epilogue
__global__ __launch_bounds__(TPB) void gemm_gradupd(
    const float* __restrict__ R, const float* __restrict__ Amat,
    float* __restrict__ zb, float* __restrict__ yb,
    const float* __restrict__ lrs, float coef,
    float* __restrict__ diffArr, int iter)
{
    if (iter > 0 && fista_done(diffArr, iter)) return;
    __shared__ float As[16][68];
    __shared__ float Bs[16][68];
    __shared__ float red[TPB];
    const int tid = threadIdx.x;
    const int tx = tid & 15, ty = tid >> 4;
    const int m0 = blockIdx.y << 6;  // rows [0,1024)
    const int n0 = blockIdx.x << 6;  // h cols
    float acc[4][4] = {};

    for (int k0 = 0; k0 < HWD; k0 += 16) {
        { // A = resid, k-contiguous
            const int m = tid >> 2, kk = (tid & 3) << 2;
            const float4 v = *(const float4*)(R + (long)(m0 + m) * HWD + (k0 + kk));
            As[kk + 0][m] = v.x; As[kk + 1][m] = v.y; As[kk + 2][m] = v.z; As[kk + 3][m] = v.w;
        }
        { // B = Amat[k][n], n-contiguous
            const int kk = tid >> 4, nn = (tid & 15) << 2;
            *(float4*)&Bs[kk][nn] = *(const float4*)(Amat + (long)(k0 + kk) * HWD + (n0 + nn));
        }
        __syncthreads();
        #pragma unroll
        for (int k = 0; k < 16; ++k) {
            const float4 ra = *(const float4*)&As[k][ty << 2];
            const float4 rb = *(const float4*)&Bs[k][tx << 2];
            FMA16();
        }
        __syncthreads();
    }

    const float lr = lrs[0], sh = lrs[1];
    const int mg = m0 + (ty << 2), ng = n0 + (tx << 2);
    float loc = 0.f;
    #pragma unroll
    for (int i = 0; i < 4; ++i) {
        #pragma unroll
        for (int j = 0; j < 4; ++j) {
            const long off = (long)(mg + i) * HWD + (ng + j);
            const float zo = zb[off];
            const float p = yb[off] - lr * acc[i][j];
            const float ap = fabsf(p) - sh;
            const float zn = ap > 0.f ? copysignf(ap, p) : 0.f;
            zb[off] = zn;
            yb[off] = zn + coef * (zn - zo);
            loc += fabsf(zn - zo);
        }
    }
    red[tid] = loc; __syncthreads();
    for (int s = 128; s > 0; s >>= 1) { if (tid < s) red[tid] += red[tid + s]; __syncthreads(); }
    if (tid == 0) atomicAdd(&diffArr[iter], red[0]);
}

__global__ __launch_bounds__(TPB) void softmax_rows(float* __restrict__ S) {
    float* r = S + (long)blockIdx.x * HWD;
    const int tid = threadIdx.x;
    __shared__ float red[TPB];
    float mx = -3.4e38f;
    for (int i = tid; i < HWD; i += TPB) mx = fmaxf(mx, r[i]);
    red[tid] = mx; __syncthreads();
    for (int s = 128; s > 0; s >>= 1) { if (tid < s) red[tid] = fmaxf(red[tid], red[tid + s]); __syncthreads(); }
    mx = red[0]; __syncthreads();
    float sum = 0.f;
    for (int i = tid; i < HWD; i += TPB) { const float e = expf(r[i] - mx); r[i] = e; sum += e; }
    red[tid] = sum; __syncthreads();
    for (int s = 128; s > 0; s >>= 1) { if (tid < s) red[tid] += red[tid + s]; __syncthreads(); }
    const float inv = 1.0f / red[0];
    for (int i = tid; i < HWD; i += TPB) r[i] *= inv;
}

__global__ __launch_bounds__(TPB) void groupnorm_x(const float* __restrict__ contc,
                                                   const float* __restrict__ meanc,
                                                   const float* __restrict__ stdc,
                                                   float* __restrict__ x) {
    const long base = (long)blockIdx.x * HWD + (long)threadIdx.x * GS;
    float v[GS];
    float mu = 0.f;
    #pragma unroll
    for (int j = 0; j < GS; ++j) { v[j] = contc[base + j]; mu += v[j]; }
    mu *= (1.0f / 9.0f);
    float var = 0.f;
    #pragma unroll
    for (int j = 0; j < GS; ++j) { const float d = v[j] - mu; var += d * d; }
    var *= (1.0f / 8.0f);  // ddof=1
    const float rs = 1.0f / sqrtf(var + 1e-5f);
    #pragma unroll
    for (int j = 0; j < GS; ++j)
        x[base + j] = (v[j] - mu) * rs * stdc[base + j] + meanc[base + j];
}

// one power-iteration step: wout = (WtW @ (win/||win||)); normalization folded post-dot
__global__ __launch_bounds__(TPB) void power_iter(const float* __restrict__ WtW,
                                                  const float* __restrict__ win,
                                                  float* __restrict__ wout) {
    __shared__ float red[TPB];
    const int tid = threadIdx.x;
    float s = 0.f;
    for (int i = tid; i < HWD; i += TPB) { const float v = win[i]; s += v * v; }
    red[tid] = s; __syncthreads();
    for (int st = 128; st > 0; st >>= 1) { if (tid < st) red[tid] += red[tid + st]; __syncthreads(); }
    const float ninv = 1.0f / sqrtf(red[0]);
    const int row = (blockIdx.x << 2) + (tid >> 6);
    const int lane = tid & 63;
    const float* wr = WtW + (long)row * HWD;
    float d = 0.f;
    for (int j = lane; j < HWD; j += 64) d += wr[j] * win[j];
    #pragma unroll
    for (int o = 32; o > 0; o >>= 1) d += __shfl_down(d, o);
    if (lane == 0) wout[row] = d * ninv;
}

// L = (w . WtW w) / (w . w):  Lnum via atomics, Lden by block 0
__global__ __launch_bounds__(TPB) void kernelL(const float* __restrict__ WtW,
                                               const float* __restrict__ w,
                                               float* __restrict__ Lnum, float* __restrict__ Lden) {
    __shared__ float red[TPB];
    const int tid = threadIdx.x;
    const int row = (blockIdx.x << 2) + (tid >> 6);
    const int lane = tid & 63;
    const float* wr = WtW + (long)row * HWD;
    float d = 0.f;
    for (int j = lane; j < HWD; j += 64) d += wr[j] * w[j];
    #pragma unroll
    for (int o = 32; o > 0; o >>= 1) d += __shfl_down(d, o);
    red[tid] = (lane == 0) ? d * w[row] : 0.f;
    __syncthreads();
    for (int s = 128; s > 0; s >>= 1) { if (tid < s) red[tid] += red[tid + s]; __syncthreads(); }
    if (tid == 0) atomicAdd(Lnum, red[0]);
    if (blockIdx.x == 0) {
        __syncthreads();
        float s2 = 0.f;
        for (int i = tid; i < HWD; i += TPB) { const float v = w[i]; s2 += v * v; }
        red[tid] = s2; __syncthreads();
        for (int s = 128; s > 0; s >>= 1) { if (tid < s) red[tid] += red[tid + s]; __syncthreads(); }
        if (tid == 0) *Lden = red[0];
    }
}

__global__ void lr_fin(const float* __restrict__ Lnum, const float* __restrict__ Lden,
                       float* __restrict__ lrs) {
    const float lr = Lden[0] / Lnum[0];  // 1/L
    lrs[0] = lr;
    lrs[1] = ALPHA * lr;
}

__global__ void init_small(float* __restrict__ wvec, float* __restrict__ diffArr,
                           float* __restrict__ Lnum) {
    const int tid = threadIdx.x;
    for (int i = tid; i < HWD; i += TPB) wvec[i] = (float)(1.0 / 48.0);  // 1/sqrt(2304)
    if (tid < 43) diffArr[tid] = 0.f;
    if (tid == 64) Lnum[0] = 0.f;
}

__global__ void zero_kernel(float4* __restrict__ p, long n4) {
    long i = (long)blockIdx.x * blockDim.x + threadIdx.x;
    const long st = (long)gridDim.x * blockDim.x;
    for (; i < n4; i += st) p[i] = make_float4(0.f, 0.f, 0.f, 0.f);
}

__global__ void copy_kernel(const float4* __restrict__ s, float4* __restrict__ d, long n4) {
    long i = (long)blockIdx.x * blockDim.x + threadIdx.x;
    const long st = (long)gridDim.x * blockDim.x;
    for (; i < n4; i += st) d[i] = s[i];
}

extern "C" void kernel_launch(void* const* d_in, const int* in_sizes, int n_in,
                              void* d_out, int out_size, void* d_ws, size_t ws_size,
                              hipStream_t stream) {
    (void)in_sizes; (void)n_in; (void)out_size;
    const float* content = (const float*)d_in[0];
    const float* style   = (const float*)d_in[1];
    const float* ckey    = (const float*)d_in[2];
    const float* skey    = (const float*)d_in[3];
    const float* f_w = (const float*)d_in[4];
    const float* f_b = (const float*)d_in[5];
    const float* g_w = (const float*)d_in[6];
    const float* g_b = (const float*)d_in[7];
    const float* h_w = (const float*)d_in[8];
    const float* h_b = (const float*)d_in[9];
    const float* Amat = (const float*)d_in[10];
    float* ws = (float*)d_ws;

    // workspace layout (floats), phase-overlapped:
    //   [0, SBIG)           : S logits/softmax (P1-2) -> cont_c @0 (SZ), x @SZ (SZ), WtW @2*SZ (P3+)
    //   b1: F -> mean_chw -> z ;  b2: G -> std_chw -> y ;  b3: H -> mean_c -> resid ; b4: std_c
    float* Sbuf  = ws;
    float* contc = ws;
    float* xbuf  = ws + SZ;
    float* WtW   = ws + 2 * SZ;
    float* b1 = ws + SBIG;
    float* b2 = b1 + SZ;
    float* b3 = b2 + SZ;
    float* b4 = b3 + SZ;
    float* w_a = b4 + SZ;
    float* w_b = w_a + HWD;
    float* lrs = w_b + HWD;
    float* Lnum = lrs + 2;
    float* Lden = Lnum + 1;
    float* diffArr = Lden + 1;

    if (ws_size < (size_t)(SBIG + 4 * SZ + 8192) * sizeof(float)) return;

    const long CHW = (long)CDIM * HWD;

    init_small<<<1, TPB, 0, stream>>>(w_a, diffArr, Lnum);

    // conv1x1: F = f_w@ckey+f_b ; G ; H  (M=512, N=2304, K=512)
    gemm_f32<1><<<dim3(36, 8, 2), TPB, 0, stream>>>(f_w, 0, CDIM, 1, ckey, CHW, HWD, 1,
                                                    b1, CHW, HWD, 1, CDIM, f_b, nullptr, nullptr, 0);
    gemm_f32<1><<<dim3(36, 8, 2), TPB, 0, stream>>>(g_w, 0, CDIM, 1, skey, CHW, HWD, 1,
                                                    b2, CHW, HWD, 1, CDIM, g_b, nullptr, nullptr, 0);
    gemm_f32<1><<<dim3(36, 8, 2), TPB, 0, stream>>>(h_w, 0, CDIM, 1, style, CHW, HWD, 1,
                                                    b3, CHW, HWD, 1, CDIM, h_b, nullptr, nullptr, 0);
    // logits = F^T G  (M=N=2304, K=512)
    gemm_f32<0><<<dim3(36, 36, 2), TPB, 0, stream>>>(b1, CHW, 1, HWD, b2, CHW, HWD, 1,
                                                     Sbuf, (long)HWD * HWD, HWD, 1, CDIM,
                                                     nullptr, nullptr, nullptr, 0);
    softmax_rows<<<BATCH * HWD, TPB, 0, stream>>>(Sbuf);
    // mean/std (writes transposed [b][c][q] into b1/b2)
    gemm_meanstd<<<dim3(8, 36, 2), TPB, 0, stream>>>(Sbuf, b3, b1, b2);
    // projections: out[n,m] = sum_h f[n,h] * A[m,h]  (M=1024, N=2304, K=2304)
    gemm_f32<0><<<dim3(36, 16, 1), TPB, 0, stream>>>(b1, 0, HWD, 1, Amat, 0, 1, HWD,
                                                     b3, 0, HWD, 1, HWD, nullptr, nullptr, nullptr, 0);
    gemm_f32<0><<<dim3(36, 16, 1), TPB, 0, stream>>>(b2, 0, HWD, 1, Amat, 0, 1, HWD,
                                                     b4, 0, HWD, 1, HWD, nullptr, nullptr, nullptr, 0);
    gemm_f32<0><<<dim3(36, 16, 1), TPB, 0, stream>>>(content, 0, HWD, 1, Amat, 0, 1, HWD,
                                                     contc, 0, HWD, 1, HWD, nullptr, nullptr, nullptr, 0);
    // group norm + scale/shift -> x
    groupnorm_x<<<BATCH * CDIM, TPB, 0, stream>>>(contc, b3, b4, xbuf);
    // WtW = A^T A  (M=N=K=2304)
    gemm_f32<0><<<dim3(36, 36, 1), TPB, 0, stream>>>(Amat, 0, 1, HWD, Amat, 0, HWD, 1,
                                                     WtW, 0, HWD, 1, HWD, nullptr, nullptr, nullptr, 0);
    // 100 power-iteration steps (ping-pong w_a/w_b; ends in w_a)
    for (int it = 0; it < 100; ++it) {
        const float* win = (it & 1) ? w_b : w_a;
        float* wout = (it & 1) ? w_a : w_b;
        power_iter<<<576, TPB, 0, stream>>>(WtW, win, wout);
    }
    kernelL<<<576, TPB, 0, stream>>>(WtW, w_a, Lnum, Lden);
    lr_fin<<<1, 1, 0, stream>>>(Lnum, Lden, lrs);

    // z = y = 0 (b1,b2 contiguous)
    zero_kernel<<<2048, TPB, 0, stream>>>((float4*)b1, (2 * SZ) / 4);

    // FISTA: 43 iterations; momentum coefficients are data-independent
    float t = 1.0f;
    for (int it = 0; it < 43; ++it) {
        const float tn = (1.0f + sqrtf(1.0f + 4.0f * t * t)) * 0.5f;
        const float coef = (t - 1.0f) / tn;
        t = tn;
        // resid = y @ A^T - x   (M=1024, N=2304, K=2304)
        gemm_f32<2><<<dim3(36, 16, 1), TPB, 0, stream>>>(b2, 0, HWD, 1, Amat, 0, 1, HWD,
                                                         b3, 0, HWD, 1, HWD,
                                                         nullptr, xbuf, diffArr, it);
        // grad = resid @ A, fused softshrink/momentum/diff update
        gemm_gradupd<<<dim3(36, 16, 1), TPB, 0, stream>>>(b3, Amat, b1, b2, lrs, coef, diffArr, it);
    }

    copy_kernel<<<2048, TPB, 0, stream>>>((const float4*)b1, (float4*)d_out, SZ / 4);
}

// Round 2
// 3151.496 us; speedup vs baseline: 6.2637x; 6.2637x over previous
//
#include <hip/hip_runtime.h>
#include <math.h>

#define TPB 256

typedef _Float16 f16;
typedef _Float16 half8 __attribute__((ext_vector_type(8)));
typedef _Float16 f16x2 __attribute__((ext_vector_type(2)));
typedef _Float16 f16x4 __attribute__((ext_vector_type(4)));
typedef float floatx4 __attribute__((ext_vector_type(4)));

static constexpr int CDIM = 512;
static constexpr int HWD = 2304;
static constexpr float ALPHA = 0.05f;
static constexpr float TOLF = 4.608e-4f;   // B*HW*1e-7

enum { EPI_F32 = 0, EPI_F16BIASN = 1, EPI_F16BIASM = 2, EPI_F16 = 3,
       EPI_WTW = 4, EPI_MEANSTD = 5, EPI_FISTA = 6 };

__device__ __forceinline__ bool fista_done(const float* __restrict__ diffArr, int iter) {
    bool done = false;
    for (int j = 0; j < iter; ++j) done = done || (diffArr[j] <= TOLF);
    return done;
}

// Generic fp16 MFMA GEMM: C[m,n] = sum_k A[m][k]*B[n][k]  (both operands k-contig)
// 128x128 tile, BK=64, 256 threads = 4 waves (2x2), per-wave 64x64 via 4x4 frags of 16x16x32.
// LDS XOR-swizzle: 16B chunk s of row R stored at slot s^(R&7)  (2-way bank conflict = free).
template<int EPI>
__global__ __launch_bounds__(TPB) void mgemm(
    const f16* __restrict__ A, long a_bs, int lda,
    const f16* __restrict__ B, long b_bs, int ldb,
    void* __restrict__ C0, long c_bs, int ldc,
    void* __restrict__ C1,
    int K,
    const float* __restrict__ bias,
    const float* __restrict__ xAf,
    float* __restrict__ zf, float* __restrict__ yf, f16* __restrict__ yhp,
    const float* __restrict__ lrs, float coef,
    float* __restrict__ diffArr, int iter)
{
    if (EPI == EPI_FISTA) {
        if (iter > 0 && fista_done(diffArr, iter)) return;
    }
    __shared__ f16 As[128 * 64];
    __shared__ f16 Bs[128 * 64];
    const int tid = threadIdx.x;
    const int wid = tid >> 6, lane = tid & 63;
    const int wr = wid >> 1, wc = wid & 1;
    const int m0 = blockIdx.y << 7, n0 = blockIdx.x << 7;
    const f16* Ab = A + (long)blockIdx.z * a_bs;
    const f16* Bb = B + (long)blockIdx.z * b_bs;

    floatx4 acc[4][4] = {};
    floatx4 acc2[4][4] = {};   // only used by MEANSTD (DCE'd otherwise)

    for (int k0 = 0; k0 < K; k0 += 64) {
        #pragma unroll
        for (int p = 0; p < 4; ++p) {
            const int i = p * 256 + tid;
            const int R = i >> 3, s = i & 7;
            const int sl = s ^ (R & 7);
            *(int4*)&As[R * 64 + sl * 8] = *(const int4*)(Ab + (long)(m0 + R) * lda + k0 + s * 8);
            *(int4*)&Bs[R * 64 + sl * 8] = *(const int4*)(Bb + (long)(n0 + R) * ldb + k0 + s * 8);
        }
        __syncthreads();
        #pragma unroll
        for (int kk = 0; kk < 2; ++kk) {
            half8 af[4], bf[4];
            const int rl = lane & 15, kg = lane >> 4;
            const int j = kk * 4 + kg;
            #pragma unroll
            for (int f = 0; f < 4; ++f) {
                const int ra = wr * 64 + f * 16 + rl;
                af[f] = *(const half8*)&As[ra * 64 + ((j ^ (ra & 7)) * 8)];
                const int rb = wc * 64 + f * 16 + rl;
                bf[f] = *(const half8*)&Bs[rb * 64 + ((j ^ (rb & 7)) * 8)];
            }
            #pragma unroll
            for (int fi = 0; fi < 4; ++fi) {
                #pragma unroll
                for (int fj = 0; fj < 4; ++fj) {
                    acc[fi][fj] = __builtin_amdgcn_mfma_f32_16x16x32_f16(af[fi], bf[fj], acc[fi][fj], 0, 0, 0);
                    if constexpr (EPI == EPI_MEANSTD) {
                        half8 bq = bf[fj] * bf[fj];
                        acc2[fi][fj] = __builtin_amdgcn_mfma_f32_16x16x32_f16(af[fi], bq, acc2[fi][fj], 0, 0, 0);
                    }
                }
            }
        }
        __syncthreads();
    }

    const int rl = lane & 15, rg = lane >> 4;
    const int bz = blockIdx.z;
    float loc = 0.f;
    float lr = 0.f, sh = 0.f;
    if constexpr (EPI == EPI_FISTA) { lr = lrs[0]; sh = lrs[1]; }

    #pragma unroll
    for (int fi = 0; fi < 4; ++fi) {
        #pragma unroll
        for (int fj = 0; fj < 4; ++fj) {
            #pragma unroll
            for (int r = 0; r < 4; ++r) {
                const int row = m0 + wr * 64 + fi * 16 + rg * 4 + r;
                const int col = n0 + wc * 64 + fj * 16 + rl;
                const float v = acc[fi][fj][r];
                if constexpr (EPI == EPI_F32) {
                    ((float*)C0)[bz * c_bs + (long)row * ldc + col] = v;
                } else if constexpr (EPI == EPI_F16BIASN) {
                    ((f16*)C0)[bz * c_bs + (long)row * ldc + col] = (f16)(v + bias[col]);
                } else if constexpr (EPI == EPI_F16BIASM) {
                    ((f16*)C0)[bz * c_bs + (long)row * ldc + col] = (f16)(v + bias[row]);
                } else if constexpr (EPI == EPI_F16) {
                    ((f16*)C0)[bz * c_bs + (long)row * ldc + col] = (f16)v;
                } else if constexpr (EPI == EPI_WTW) {
                    ((float*)C0)[(long)row * ldc + col] = v;
                    ((f16*)C1)[(long)row * ldc + col] = (f16)v;
                } else if constexpr (EPI == EPI_MEANSTD) {
                    const float m_ = v;
                    float s2 = acc2[fi][fj][r] - m_ * m_;
                    const long o = ((long)bz * CDIM + col) * HWD + row;
                    ((f16*)C0)[o] = (f16)m_;
                    ((f16*)C1)[o] = (f16)sqrtf(s2 > 0.f ? s2 : 0.f);
                } else {  // EPI_FISTA
                    const long off = (long)row * HWD + col;
                    const float grad = v - xAf[off];
                    const float zo = zf[off];
                    const float p = yf[off] - lr * grad;
                    const float ap = fabsf(p) - sh;
                    const float zn = ap > 0.f ? copysignf(ap, p) : 0.f;
                    zf[off] = zn;
                    const float yn = zn + coef * (zn - zo);
                    yf[off] = yn;
                    yhp[off] = (f16)yn;
                    loc += fabsf(zn - zo);
                }
            }
        }
    }
    if constexpr (EPI == EPI_FISTA) {
        __shared__ float red[TPB];
        red[tid] = loc; __syncthreads();
        for (int s = 128; s > 0; s >>= 1) { if (tid < s) red[tid] += red[tid + s]; __syncthreads(); }
        if (tid == 0) atomicAdd(&diffArr[iter], red[0]);
    }
}

// f32 [b][R][Cc] -> f16 [b][Cc][R]
__global__ __launch_bounds__(TPB) void tcvt(const float* __restrict__ in, long in_bs,
                                            f16* __restrict__ out, long out_bs, int R, int Cc) {
    __shared__ float t[32][33];
    const int b = blockIdx.z;
    const int r0 = blockIdx.y << 5, c0 = blockIdx.x << 5;
    const int tx = threadIdx.x & 31, ty = threadIdx.x >> 5;
    const float* ib = in + (long)b * in_bs;
    #pragma unroll
    for (int p = 0; p < 4; ++p) {
        const int r = ty + p * 8;
        t[r][tx] = ib[(long)(r0 + r) * Cc + c0 + tx];
    }
    __syncthreads();
    f16* ob = out + (long)b * out_bs;
    #pragma unroll
    for (int p = 0; p < 4; ++p) {
        const int c = ty + p * 8;
        ob[(long)(c0 + c) * R + r0 + tx] = (f16)t[tx][c];
    }
}

__global__ void cvt16(const float4* __restrict__ in, f16x4* __restrict__ out, long n4) {
    long i = (long)blockIdx.x * blockDim.x + threadIdx.x;
    const long st = (long)gridDim.x * blockDim.x;
    for (; i < n4; i += st) {
        const float4 v = in[i];
        f16x4 o; o.x = (f16)v.x; o.y = (f16)v.y; o.z = (f16)v.z; o.w = (f16)v.w;
        out[i] = o;
    }
}

// softmax over rows of Sf (4608 rows x 2304), write fp16
__global__ __launch_bounds__(TPB) void softmax_h(float* __restrict__ Sf, f16* __restrict__ Sh) {
    float* r = Sf + (long)blockIdx.x * HWD;
    f16* o = Sh + (long)blockIdx.x * HWD;
    const int tid = threadIdx.x;
    __shared__ float red[TPB];
    float mx = -3.4e38f;
    for (int i = tid; i < HWD; i += TPB) mx = fmaxf(mx, r[i]);
    red[tid] = mx; __syncthreads();
    for (int s = 128; s > 0; s >>= 1) { if (tid < s) red[tid] = fmaxf(red[tid], red[tid + s]); __syncthreads(); }
    mx = red[0]; __syncthreads();
    float sum = 0.f;
    for (int i = tid; i < HWD; i += TPB) { const float e = expf(r[i] - mx); r[i] = e; sum += e; }
    red[tid] = sum; __syncthreads();
    for (int s = 128; s > 0; s >>= 1) { if (tid < s) red[tid] += red[tid + s]; __syncthreads(); }
    const float inv = 1.0f / red[0];
    for (int i = tid; i < HWD; i += TPB) o[i] = (f16)(r[i] * inv);
}

// group-norm (256 groups of 9) + scale/shift -> x (fp16)
__global__ __launch_bounds__(TPB) void groupnorm_x(const float* __restrict__ contc,
                                                   const float* __restrict__ meanc,
                                                   const float* __restrict__ stdc,
                                                   f16* __restrict__ xh) {
    const long base = (long)blockIdx.x * HWD + (long)threadIdx.x * 9;
    float v[9];
    float mu = 0.f;
    #pragma unroll
    for (int j = 0; j < 9; ++j) { v[j] = contc[base + j]; mu += v[j]; }
    mu *= (1.0f / 9.0f);
    float var = 0.f;
    #pragma unroll
    for (int j = 0; j < 9; ++j) { const float d = v[j] - mu; var += d * d; }
    var *= (1.0f / 8.0f);
    const float rs = 1.0f / sqrtf(var + 1e-5f);
    #pragma unroll
    for (int j = 0; j < 9; ++j)
        xh[base + j] = (f16)((v[j] - mu) * rs * (float)stdc[base + j] + (float)meanc[base + j]);
}

// power-iteration matvec on fp16 matrix, with input normalization folded in
__global__ __launch_bounds__(TPB) void matvec_h(const f16* __restrict__ Wm,
                                                const float* __restrict__ win,
                                                float* __restrict__ wout) {
    __shared__ float red[TPB];
    const int tid = threadIdx.x;
    float s = 0.f;
    for (int i = tid; i < HWD; i += TPB) { const float v = win[i]; s += v * v; }
    red[tid] = s; __syncthreads();
    for (int st = 128; st > 0; st >>= 1) { if (tid < st) red[tid] += red[tid + st]; __syncthreads(); }
    const float ninv = rsqrtf(red[0]);
    const int row = (blockIdx.x << 2) + (tid >> 6);
    const int lane = tid & 63;
    const f16x2* wr2 = (const f16x2*)(Wm + (long)row * HWD);
    float d = 0.f;
    for (int j = lane; j < HWD / 2; j += 64) {
        const f16x2 p = wr2[j];
        d += (float)p.x * win[2 * j] + (float)p.y * win[2 * j + 1];
    }
    #pragma unroll
    for (int o = 32; o > 0; o >>= 1) d += __shfl_down(d, o);
    if (lane == 0) wout[row] = d * ninv;
}

// L = (w . Wf w) / (w . w)
__global__ __launch_bounds__(TPB) void kernelL(const float* __restrict__ Wf,
                                               const float* __restrict__ w,
                                               float* __restrict__ Lnum, float* __restrict__ Lden) {
    __shared__ float red[TPB];
    const int tid = threadIdx.x;
    const int row = (blockIdx.x << 2) + (tid >> 6);
    const int lane = tid & 63;
    const float* wr = Wf + (long)row * HWD;
    float d = 0.f;
    for (int j = lane; j < HWD; j += 64) d += wr[j] * w[j];
    #pragma unroll
    for (int o = 32; o > 0; o >>= 1) d += __shfl_down(d, o);
    red[tid] = (lane == 0) ? d * w[row] : 0.f;
    __syncthreads();
    for (int s = 128; s > 0; s >>= 1) { if (tid < s) red[tid] += red[tid + s]; __syncthreads(); }
    if (tid == 0) atomicAdd(Lnum, red[0]);
    if (blockIdx.x == 0) {
        __syncthreads();
        float s2 = 0.f;
        for (int i = tid; i < HWD; i += TPB) { const float v = w[i]; s2 += v * v; }
        red[tid] = s2; __syncthreads();
        for (int s = 128; s > 0; s >>= 1) { if (tid < s) red[tid] += red[tid + s]; __syncthreads(); }
        if (tid == 0) *Lden = red[0];
    }
}

__global__ void lr_fin(const float* __restrict__ Lnum, const float* __restrict__ Lden,
                       float* __restrict__ lrs) {
    const float lr = Lden[0] / Lnum[0];
    lrs[0] = lr;
    lrs[1] = ALPHA * lr;
}

__global__ void init_small(float* __restrict__ wvec, float* __restrict__ diffArr,
                           float* __restrict__ Lnum) {
    const int tid = threadIdx.x;
    for (int i = tid; i < HWD; i += TPB) wvec[i] = (float)(1.0 / 48.0);
    if (tid < 43) diffArr[tid] = 0.f;
    if (tid == 64) Lnum[0] = 0.f;
}

__global__ void zero_kernel(float4* __restrict__ p, long n4) {
    long i = (long)blockIdx.x * blockDim.x + threadIdx.x;
    const long st = (long)gridDim.x * blockDim.x;
    for (; i < n4; i += st) p[i] = make_float4(0.f, 0.f, 0.f, 0.f);
}

__global__ void copy_kernel(const float4* __restrict__ s, float4* __restrict__ d, long n4) {
    long i = (long)blockIdx.x * blockDim.x + threadIdx.x;
    const long st = (long)gridDim.x * blockDim.x;
    for (; i < n4; i += st) d[i] = s[i];
}

extern "C" void kernel_launch(void* const* d_in, const int* in_sizes, int n_in,
                              void* d_out, int out_size, void* d_ws, size_t ws_size,
                              hipStream_t stream) {
    (void)in_sizes; (void)n_in; (void)out_size;
    const float* content = (const float*)d_in[0];
    const float* style   = (const float*)d_in[1];
    const float* ckey    = (const float*)d_in[2];
    const float* skey    = (const float*)d_in[3];
    const float* f_w = (const float*)d_in[4];
    const float* f_b = (const float*)d_in[5];
    const float* g_w = (const float*)d_in[6];
    const float* g_b = (const float*)d_in[7];
    const float* h_w = (const float*)d_in[8];
    const float* h_b = (const float*)d_in[9];
    const float* Amat = (const float*)d_in[10];

    if (ws_size < 79500000) return;
    char* W = (char*)d_ws;

    const long E16 = (long)HWD * CDIM;          // 1,179,648
    const long EHH = (long)HWD * HWD;           // 5,308,416
    // ---- arena (byte offsets), phase-overlapped ----
    // R0 @0 (42,467,328): keysT -> Sf -> {Ah,At,Wh,W4h} -> W2h -> contc -> z,y,yh
    // R1 @42,467,328 (21,233,664): Sh -> meanc,stdc -> Wf -> xAf
    // R2 @63,700,992 (14,155,776): Fh,Gh,Hh -> meanx,stdx,conth -> xh
    f16*  ckeyT = (f16*)(W + 0);
    f16*  skeyT = (f16*)(W + 4718592);
    f16*  styleT= (f16*)(W + 9437184);
    float* Sf   = (float*)(W + 0);
    f16*  Ah    = (f16*)(W + 0);
    f16*  At    = (f16*)(W + 10616832);
    f16*  Wh    = (f16*)(W + 21233664);
    f16*  W4h   = (f16*)(W + 31850496);
    f16*  W2h   = (f16*)(W + 0);
    float* contc= (float*)(W + 21233664);
    float* zf   = (float*)(W + 0);
    float* yf   = (float*)(W + 9437184);
    f16*  yh    = (f16*)(W + 31850496);
    f16*  Sh    = (f16*)(W + 42467328);
    float* meanc= (float*)(W + 42467328);
    float* stdc = (float*)(W + 42467328 + 9437184);
    float* Wf   = (float*)(W + 42467328);
    float* xAf  = (float*)(W + 42467328);
    f16*  Fh    = (f16*)(W + 63700992);
    f16*  Gh    = (f16*)(W + 63700992 + 4718592);
    f16*  Hh    = (f16*)(W + 63700992 + 9437184);
    f16*  meanx = (f16*)(W + 63700992);
    f16*  stdx  = (f16*)(W + 63700992 + 4718592);
    f16*  conth = (f16*)(W + 63700992 + 9437184);
    f16*  xh    = (f16*)(W + 63700992);
    float* w_a  = (float*)(W + 77856768);
    float* w_b  = (float*)(W + 77856768 + 9216);
    float* lrs  = (float*)(W + 77856768 + 18432);
    float* Lnum = (float*)(W + 77856768 + 18440);
    float* Lden = (float*)(W + 77856768 + 18444);
    float* diffArr = (float*)(W + 77856768 + 18448);
    f16*  fwh   = (f16*)(W + 77875712);
    f16*  gwh   = (f16*)(W + 77875712 + 524288);
    f16*  hwh   = (f16*)(W + 77875712 + 1048576);

    init_small<<<1, TPB, 0, stream>>>(w_a, diffArr, Lnum);

    // weight + key conversions
    cvt16<<<256, TPB, 0, stream>>>((const float4*)f_w, (f16x4*)fwh, (long)CDIM * CDIM / 4);
    cvt16<<<256, TPB, 0, stream>>>((const float4*)g_w, (f16x4*)gwh, (long)CDIM * CDIM / 4);
    cvt16<<<256, TPB, 0, stream>>>((const float4*)h_w, (f16x4*)hwh, (long)CDIM * CDIM / 4);
    tcvt<<<dim3(72, 16, 2), TPB, 0, stream>>>(ckey, E16, ckeyT, E16, CDIM, HWD);
    tcvt<<<dim3(72, 16, 2), TPB, 0, stream>>>(skey, E16, skeyT, E16, CDIM, HWD);
    tcvt<<<dim3(72, 16, 2), TPB, 0, stream>>>(style, E16, styleT, E16, CDIM, HWD);

    // convs: Fh[s][c], Gh[s][c] (bias over n=c);  Hh[c][s] (bias over m=c)
    mgemm<EPI_F16BIASN><<<dim3(4, 18, 2), TPB, 0, stream>>>(ckeyT, E16, CDIM, fwh, 0, CDIM,
        Fh, E16, CDIM, nullptr, CDIM, f_b, nullptr, nullptr, nullptr, nullptr, nullptr, 0.f, nullptr, 0);
    mgemm<EPI_F16BIASN><<<dim3(4, 18, 2), TPB, 0, stream>>>(skeyT, E16, CDIM, gwh, 0, CDIM,
        Gh, E16, CDIM, nullptr, CDIM, g_b, nullptr, nullptr, nullptr, nullptr, nullptr, 0.f, nullptr, 0);
    mgemm<EPI_F16BIASM><<<dim3(18, 4, 2), TPB, 0, stream>>>(hwh, 0, CDIM, styleT, E16, CDIM,
        Hh, E16, HWD, nullptr, CDIM, h_b, nullptr, nullptr, nullptr, nullptr, nullptr, 0.f, nullptr, 0);

    // logits = Fh . Gh^T  -> Sf f32
    mgemm<EPI_F32><<<dim3(18, 18, 2), TPB, 0, stream>>>(Fh, E16, CDIM, Gh, E16, CDIM,
        Sf, EHH, HWD, nullptr, CDIM, nullptr, nullptr, nullptr, nullptr, nullptr, nullptr, 0.f, nullptr, 0);
    softmax_h<<<2 * HWD, TPB, 0, stream>>>(Sf, Sh);

    // A conversions (into dead Sf space)
    cvt16<<<2048, TPB, 0, stream>>>((const float4*)Amat, (f16x4*)Ah, EHH / 4);
    tcvt<<<dim3(72, 72, 1), TPB, 0, stream>>>(Amat, 0, At, 0, HWD, HWD);

    // mean/std (dual MFMA), transposed write -> meanx/stdx [b*c][q]
    mgemm<EPI_MEANSTD><<<dim3(4, 18, 2), TPB, 0, stream>>>(Sh, EHH, HWD, Hh, E16, HWD,
        meanx, 0, HWD, stdx, HWD, nullptr, nullptr, nullptr, nullptr, nullptr, nullptr, 0.f, nullptr, 0);

    cvt16<<<2048, TPB, 0, stream>>>((const float4*)content, (f16x4*)conth, (long)2 * E16 / 4);

    // projections -> f32 [1024][2304]
    mgemm<EPI_F32><<<dim3(18, 8, 1), TPB, 0, stream>>>(meanx, 0, HWD, Ah, 0, HWD,
        meanc, 0, HWD, nullptr, HWD, nullptr, nullptr, nullptr, nullptr, nullptr, nullptr, 0.f, nullptr, 0);
    mgemm<EPI_F32><<<dim3(18, 8, 1), TPB, 0, stream>>>(stdx, 0, HWD, Ah, 0, HWD,
        stdc, 0, HWD, nullptr, HWD, nullptr, nullptr, nullptr, nullptr, nullptr, nullptr, 0.f, nullptr, 0);
    mgemm<EPI_F32><<<dim3(18, 8, 1), TPB, 0, stream>>>(conth, 0, HWD, Ah, 0, HWD,
        contc, 0, HWD, nullptr, HWD, nullptr, nullptr, nullptr, nullptr, nullptr, nullptr, 0.f, nullptr, 0);

    groupnorm_x<<<1024, TPB, 0, stream>>>(contc, meanc, stdc, xh);

    // WtW (f32 + f16), then W2 = Wh^2, W4 = W2^2 (fp16; symmetric so [n][k] is fine)
    mgemm<EPI_WTW><<<dim3(18, 18, 1), TPB, 0, stream>>>(At, 0, HWD, At, 0, HWD,
        Wf, 0, HWD, Wh, HWD, nullptr, nullptr, nullptr, nullptr, nullptr, nullptr, 0.f, nullptr, 0);
    mgemm<EPI_F16><<<dim3(18, 18, 1), TPB, 0, stream>>>(Wh, 0, HWD, Wh, 0, HWD,
        W2h, 0, HWD, nullptr, HWD, nullptr, nullptr, nullptr, nullptr, nullptr, nullptr, 0.f, nullptr, 0);
    mgemm<EPI_F16><<<dim3(18, 18, 1), TPB, 0, stream>>>(W2h, 0, HWD, W2h, 0, HWD,
        W4h, 0, HWD, nullptr, HWD, nullptr, nullptr, nullptr, nullptr, nullptr, nullptr, 0.f, nullptr, 0);

    // 25 power iterations on W4 == 100 on W (same Krylov direction); ends in w_b
    for (int it = 0; it < 25; ++it) {
        const float* win = (it & 1) ? w_b : w_a;
        float* wout = (it & 1) ? w_a : w_b;
        matvec_h<<<HWD / 4, TPB, 0, stream>>>(W4h, win, wout);
    }
    kernelL<<<HWD / 4, TPB, 0, stream>>>(Wf, w_b, Lnum, Lden);
    lr_fin<<<1, 1, 0, stream>>>(Lnum, Lden, lrs);

    // xA (loop-invariant): xAf = xh . At^T   (overwrites dead Wf)
    mgemm<EPI_F32><<<dim3(18, 8, 1), TPB, 0, stream>>>(xh, 0, HWD, At, 0, HWD,
        xAf, 0, HWD, nullptr, HWD, nullptr, nullptr, nullptr, nullptr, nullptr, nullptr, 0.f, nullptr, 0);

    // z = y = 0, yh = 0
    zero_kernel<<<2048, TPB, 0, stream>>>((float4*)zf, (long)2 * 2 * E16 / 4);
    zero_kernel<<<1024, TPB, 0, stream>>>((float4*)yh, (long)2 * E16 / 2 / 4);

    // FISTA: grad = y@WtW - xA, one fused MFMA GEMM per iteration
    float t = 1.0f;
    for (int it = 0; it < 43; ++it) {
        const float tn = (1.0f + sqrtf(1.0f + 4.0f * t * t)) * 0.5f;
        const float coef = (t - 1.0f) / tn;
        t = tn;
        mgemm<EPI_FISTA><<<dim3(18, 8, 1), TPB, 0, stream>>>(yh, 0, HWD, Wh, 0, HWD,
            nullptr, 0, HWD, nullptr, HWD, nullptr, xAf, zf, yf, yh, lrs, coef, diffArr, it);
    }

    copy_kernel<<<2048, TPB, 0, stream>>>((const float4*)zf, (float4*)d_out, (long)2 * E16 / 4);
}

// Round 4
// 2326.181 us; speedup vs baseline: 8.4860x; 1.3548x over previous
//
#include <hip/hip_runtime.h>
#include <math.h>

#define TPB 256

typedef _Float16 f16;
typedef _Float16 half8 __attribute__((ext_vector_type(8)));
typedef _Float16 f16x2 __attribute__((ext_vector_type(2)));
typedef _Float16 f16x4 __attribute__((ext_vector_type(4)));
typedef float floatx4 __attribute__((ext_vector_type(4)));

static constexpr int CDIM = 512;
static constexpr int HWD = 2304;
static constexpr float ALPHA = 0.05f;
static constexpr float TOLF = 4.608e-4f;   // B*HW*1e-7

enum { EPI_F32 = 0, EPI_F16BIASN = 1, EPI_F16BIASM = 2, EPI_F16 = 3,
       EPI_WTW = 4, EPI_MEANSTD = 5, EPI_FISTA = 6 };

__device__ __forceinline__ bool fista_done(const float* __restrict__ diffArr, int iter) {
    bool done = false;
    for (int j = 0; j < iter; ++j) done = done || (diffArr[j] <= TOLF);
    return done;
}

// Generic fp16 MFMA GEMM: C[m,n] = sum_k A[m][k]*B[n][k]  (both operands k-contig).
// 64x64 tile, BK=64, 256 threads = 4 waves (2x2), per-wave 32x32 via 2x2 frags of 16x16x32.
// Small tile => grids of 576..2592 blocks (vs 144 at 128-tile): 2-5 blocks/CU for latency hiding.
// LDS XOR-swizzle: 16B chunk s of row R stored at slot s^(R&7) (bank-conflict-free, R1-verified).
template<int EPI>
__global__ __launch_bounds__(TPB, 3) void sgemm(
    const f16* __restrict__ A, long a_bs, int lda,
    const f16* __restrict__ B, long b_bs, int ldb,
    void* __restrict__ C0, long c_bs, int ldc,
    void* __restrict__ C1,
    int K,
    const float* __restrict__ bias,
    const f16* __restrict__ xAh,
    float* __restrict__ zf, f16* __restrict__ yhp,
    const float* __restrict__ lrs, float coef,
    float* __restrict__ diffArr, int iter)
{
    if (EPI == EPI_FISTA) {
        if (iter > 0 && fista_done(diffArr, iter)) return;
    }
    __shared__ f16 As[64 * 64];
    __shared__ f16 Bs[64 * 64];
    const int tid = threadIdx.x;
    const int wid = tid >> 6, lane = tid & 63;
    const int wr = wid >> 1, wc = wid & 1;
    const int m0 = blockIdx.y << 6, n0 = blockIdx.x << 6;
    const f16* Ab = A + (long)blockIdx.z * a_bs;
    const f16* Bb = B + (long)blockIdx.z * b_bs;

    floatx4 acc[2][2] = {};
    floatx4 acc2[2][2] = {};   // only used by MEANSTD (DCE'd otherwise)

    const int Rr = tid >> 3, s0 = tid & 7;
    const int rl = lane & 15, kg = lane >> 4;

    for (int k0 = 0; k0 < K; k0 += 64) {
        #pragma unroll
        for (int p = 0; p < 2; ++p) {
            const int R = p * 32 + Rr;
            const int sl = s0 ^ (R & 7);
            *(int4*)&As[R * 64 + sl * 8] = *(const int4*)(Ab + (long)(m0 + R) * lda + k0 + s0 * 8);
            *(int4*)&Bs[R * 64 + sl * 8] = *(const int4*)(Bb + (long)(n0 + R) * ldb + k0 + s0 * 8);
        }
        __syncthreads();
        #pragma unroll
        for (int kk = 0; kk < 2; ++kk) {
            const int j = kk * 4 + kg;
            half8 af[2], bf[2];
            #pragma unroll
            for (int f = 0; f < 2; ++f) {
                const int ra = wr * 32 + f * 16 + rl;
                af[f] = *(const half8*)&As[ra * 64 + ((j ^ (ra & 7)) * 8)];
                const int rb = wc * 32 + f * 16 + rl;
                bf[f] = *(const half8*)&Bs[rb * 64 + ((j ^ (rb & 7)) * 8)];
            }
            #pragma unroll
            for (int fi = 0; fi < 2; ++fi) {
                #pragma unroll
                for (int fj = 0; fj < 2; ++fj) {
                    acc[fi][fj] = __builtin_amdgcn_mfma_f32_16x16x32_f16(af[fi], bf[fj], acc[fi][fj], 0, 0, 0);
                    if constexpr (EPI == EPI_MEANSTD) {
                        half8 bq = bf[fj] * bf[fj];
                        acc2[fi][fj] = __builtin_amdgcn_mfma_f32_16x16x32_f16(af[fi], bq, acc2[fi][fj], 0, 0, 0);
                    }
                }
            }
        }
        __syncthreads();
    }

    const int rg = lane >> 4;
    const int bz = blockIdx.z;
    float loc = 0.f;
    float lr = 0.f, sh = 0.f;
    if constexpr (EPI == EPI_FISTA) { lr = lrs[0]; sh = lrs[1]; }

    #pragma unroll
    for (int fi = 0; fi < 2; ++fi) {
        #pragma unroll
        for (int fj = 0; fj < 2; ++fj) {
            #pragma unroll
            for (int r = 0; r < 4; ++r) {
                const int row = m0 + wr * 32 + fi * 16 + rg * 4 + r;
                const int col = n0 + wc * 32 + fj * 16 + rl;
                const float v = acc[fi][fj][r];
                if constexpr (EPI == EPI_F32) {
                    ((float*)C0)[bz * c_bs + (long)row * ldc + col] = v;
                } else if constexpr (EPI == EPI_F16BIASN) {
                    ((f16*)C0)[bz * c_bs + (long)row * ldc + col] = (f16)(v + bias[col]);
                } else if constexpr (EPI == EPI_F16BIASM) {
                    ((f16*)C0)[bz * c_bs + (long)row * ldc + col] = (f16)(v + bias[row]);
                } else if constexpr (EPI == EPI_F16) {
                    ((f16*)C0)[bz * c_bs + (long)row * ldc + col] = (f16)v;
                } else if constexpr (EPI == EPI_WTW) {
                    ((float*)C0)[(long)row * ldc + col] = v;
                    ((f16*)C1)[(long)row * ldc + col] = (f16)v;
                } else if constexpr (EPI == EPI_MEANSTD) {
                    const float m_ = v;
                    float s2 = acc2[fi][fj][r] - m_ * m_;
                    const long o = ((long)bz * CDIM + col) * HWD + row;
                    ((f16*)C0)[o] = (f16)m_;
                    ((f16*)C1)[o] = (f16)sqrtf(s2 > 0.f ? s2 : 0.f);
                } else {  // EPI_FISTA: grad = acc - xA; softshrink; momentum; y kept f16-only
                    const long off = (long)row * HWD + col;
                    const float grad = v - (float)xAh[off];
                    const float zo = zf[off];
                    const float p = (float)yhp[off] - lr * grad;
                    const float ap = fabsf(p) - sh;
                    const float zn = ap > 0.f ? copysignf(ap, p) : 0.f;
                    zf[off] = zn;
                    yhp[off] = (f16)(zn + coef * (zn - zo));
                    loc += fabsf(zn - zo);
                }
            }
        }
    }
    if constexpr (EPI == EPI_FISTA) {
        __shared__ float red[TPB];
        red[tid] = loc; __syncthreads();
        for (int s = 128; s > 0; s >>= 1) { if (tid < s) red[tid] += red[tid + s]; __syncthreads(); }
        if (tid == 0) atomicAdd(&diffArr[iter], red[0]);
    }
}

// f32 [b][R][Cc] -> f16 [b][Cc][R]
__global__ __launch_bounds__(TPB) void tcvt(const float* __restrict__ in, long in_bs,
                                            f16* __restrict__ out, long out_bs, int R, int Cc) {
    __shared__ float t[32][33];
    const int b = blockIdx.z;
    const int r0 = blockIdx.y << 5, c0 = blockIdx.x << 5;
    const int tx = threadIdx.x & 31, ty = threadIdx.x >> 5;
    const float* ib = in + (long)b * in_bs;
    #pragma unroll
    for (int p = 0; p < 4; ++p) {
        const int r = ty + p * 8;
        t[r][tx] = ib[(long)(r0 + r) * Cc + c0 + tx];
    }
    __syncthreads();
    f16* ob = out + (long)b * out_bs;
    #pragma unroll
    for (int p = 0; p < 4; ++p) {
        const int c = ty + p * 8;
        ob[(long)(c0 + c) * R + r0 + tx] = (f16)t[tx][c];
    }
}

__global__ void cvt16(const float4* __restrict__ in, f16x4* __restrict__ out, long n4) {
    long i = (long)blockIdx.x * blockDim.x + threadIdx.x;
    const long st = (long)gridDim.x * blockDim.x;
    for (; i < n4; i += st) {
        const float4 v = in[i];
        f16x4 o; o.x = (f16)v.x; o.y = (f16)v.y; o.z = (f16)v.z; o.w = (f16)v.w;
        out[i] = o;
    }
}

// row softmax with the row staged in LDS (one global read + one f16 write)
__global__ __launch_bounds__(TPB) void softmax_h(const float* __restrict__ Sf, f16* __restrict__ Sh) {
    __shared__ float row[HWD];
    __shared__ float red[TPB];
    const long base = (long)blockIdx.x * HWD;
    const int tid = threadIdx.x;
    float mx = -3.4e38f;
    for (int i = tid; i < HWD; i += TPB) { const float v = Sf[base + i]; row[i] = v; mx = fmaxf(mx, v); }
    red[tid] = mx; __syncthreads();
    for (int s = 128; s > 0; s >>= 1) { if (tid < s) red[tid] = fmaxf(red[tid], red[tid + s]); __syncthreads(); }
    mx = red[0]; __syncthreads();
    float sum = 0.f;
    for (int i = tid; i < HWD; i += TPB) { const float e = expf(row[i] - mx); row[i] = e; sum += e; }
    red[tid] = sum; __syncthreads();
    for (int s = 128; s > 0; s >>= 1) { if (tid < s) red[tid] += red[tid + s]; __syncthreads(); }
    const float inv = 1.0f / red[0];
    for (int i = tid; i < HWD; i += TPB) Sh[base + i] = (f16)(row[i] * inv);
}

// group-norm (256 groups of 9) + scale/shift -> x (fp16)
__global__ __launch_bounds__(TPB) void groupnorm_x(const float* __restrict__ contc,
                                                   const float* __restrict__ meanc,
                                                   const float* __restrict__ stdc,
                                                   f16* __restrict__ xh) {
    const long base = (long)blockIdx.x * HWD + (long)threadIdx.x * 9;
    float v[9];
    float mu = 0.f;
    #pragma unroll
    for (int j = 0; j < 9; ++j) { v[j] = contc[base + j]; mu += v[j]; }
    mu *= (1.0f / 9.0f);
    float var = 0.f;
    #pragma unroll
    for (int j = 0; j < 9; ++j) { const float d = v[j] - mu; var += d * d; }
    var *= (1.0f / 8.0f);
    const float rs = 1.0f / sqrtf(var + 1e-5f);
    #pragma unroll
    for (int j = 0; j < 9; ++j)
        xh[base + j] = (f16)((v[j] - mu) * rs * (float)stdc[base + j] + (float)meanc[base + j]);
}

// power-iteration matvec on fp16 matrix, with input normalization folded in
__global__ __launch_bounds__(TPB) void matvec_h(const f16* __restrict__ Wm,
                                                const float* __restrict__ win,
                                                float* __restrict__ wout) {
    __shared__ float red[TPB];
    const int tid = threadIdx.x;
    float s = 0.f;
    for (int i = tid; i < HWD; i += TPB) { const float v = win[i]; s += v * v; }
    red[tid] = s; __syncthreads();
    for (int st = 128; st > 0; st >>= 1) { if (tid < st) red[tid] += red[tid + st]; __syncthreads(); }
    const float ninv = rsqrtf(red[0]);
    const int row = (blockIdx.x << 2) + (tid >> 6);
    const int lane = tid & 63;
    const f16x2* wr2 = (const f16x2*)(Wm + (long)row * HWD);
    float d = 0.f;
    for (int j = lane; j < HWD / 2; j += 64) {
        const f16x2 p = wr2[j];
        d += (float)p.x * win[2 * j] + (float)p.y * win[2 * j + 1];
    }
    #pragma unroll
    for (int o = 32; o > 0; o >>= 1) d += __shfl_down(d, o);
    if (lane == 0) wout[row] = d * ninv;
}

// L = (w . Wf w) / (w . w)
__global__ __launch_bounds__(TPB) void kernelL(const float* __restrict__ Wf,
                                               const float* __restrict__ w,
                                               float* __restrict__ Lnum, float* __restrict__ Lden) {
    __shared__ float red[TPB];
    const int tid = threadIdx.x;
    const int row = (blockIdx.x << 2) + (tid >> 6);
    const int lane = tid & 63;
    const float* wr = Wf + (long)row * HWD;
    float d = 0.f;
    for (int j = lane; j < HWD; j += 64) d += wr[j] * w[j];
    #pragma unroll
    for (int o = 32; o > 0; o >>= 1) d += __shfl_down(d, o);
    red[tid] = (lane == 0) ? d * w[row] : 0.f;
    __syncthreads();
    for (int s = 128; s > 0; s >>= 1) { if (tid < s) red[tid] += red[tid + s]; __syncthreads(); }
    if (tid == 0) atomicAdd(Lnum, red[0]);
    if (blockIdx.x == 0) {
        __syncthreads();
        float s2 = 0.f;
        for (int i = tid; i < HWD; i += TPB) { const float v = w[i]; s2 += v * v; }
        red[tid] = s2; __syncthreads();
        for (int s = 128; s > 0; s >>= 1) { if (tid < s) red[tid] += red[tid + s]; __syncthreads(); }
        if (tid == 0) *Lden = red[0];
    }
}

__global__ void lr_fin(const float* __restrict__ Lnum, const float* __restrict__ Lden,
                       float* __restrict__ lrs) {
    const float lr = Lden[0] / Lnum[0];
    lrs[0] = lr;
    lrs[1] = ALPHA * lr;
}

__global__ void init_small(float* __restrict__ wvec, float* __restrict__ diffArr,
                           float* __restrict__ Lnum) {
    const int tid = threadIdx.x;
    for (int i = tid; i < HWD; i += TPB) wvec[i] = (float)(1.0 / 48.0);
    if (tid < 43) diffArr[tid] = 0.f;
    if (tid == 64) Lnum[0] = 0.f;
}

__global__ void zero_kernel(float4* __restrict__ p, long n4) {
    long i = (long)blockIdx.x * blockDim.x + threadIdx.x;
    const long st = (long)gridDim.x * blockDim.x;
    for (; i < n4; i += st) p[i] = make_float4(0.f, 0.f, 0.f, 0.f);
}

__global__ void copy_kernel(const float4* __restrict__ s, float4* __restrict__ d, long n4) {
    long i = (long)blockIdx.x * blockDim.x + threadIdx.x;
    const long st = (long)gridDim.x * blockDim.x;
    for (; i < n4; i += st) d[i] = s[i];
}

extern "C" void kernel_launch(void* const* d_in, const int* in_sizes, int n_in,
                              void* d_out, int out_size, void* d_ws, size_t ws_size,
                              hipStream_t stream) {
    (void)in_sizes; (void)n_in; (void)out_size;
    const float* content = (const float*)d_in[0];
    const float* style   = (const float*)d_in[1];
    const float* ckey    = (const float*)d_in[2];
    const float* skey    = (const float*)d_in[3];
    const float* f_w = (const float*)d_in[4];
    const float* f_b = (const float*)d_in[5];
    const float* g_w = (const float*)d_in[6];
    const float* g_b = (const float*)d_in[7];
    const float* h_w = (const float*)d_in[8];
    const float* h_b = (const float*)d_in[9];
    const float* Amat = (const float*)d_in[10];

    if (ws_size < 79500000) return;
    char* W = (char*)d_ws;

    const long E16 = (long)HWD * CDIM;          // 1,179,648
    const long EHH = (long)HWD * HWD;           // 5,308,416
    // ---- arena (byte offsets), phase-overlapped (layout proven in R1/R2) ----
    f16*  ckeyT = (f16*)(W + 0);
    f16*  skeyT = (f16*)(W + 4718592);
    f16*  styleT= (f16*)(W + 9437184);
    float* Sf   = (float*)(W + 0);
    f16*  Ah    = (f16*)(W + 0);
    f16*  At    = (f16*)(W + 10616832);
    f16*  Wh    = (f16*)(W + 21233664);
    f16*  W4h   = (f16*)(W + 31850496);
    f16*  W2h   = (f16*)(W + 0);
    float* contc= (float*)(W + 21233664);
    float* zf   = (float*)(W + 0);
    f16*  yh    = (f16*)(W + 31850496);         // overwrites W4h after matvecs done
    f16*  Sh    = (f16*)(W + 42467328);
    float* meanc= (float*)(W + 42467328);
    float* stdc = (float*)(W + 42467328 + 9437184);
    float* Wf   = (float*)(W + 42467328);
    f16*  xAh   = (f16*)(W + 42467328);         // overwrites Wf after kernelL
    f16*  Fh    = (f16*)(W + 63700992);
    f16*  Gh    = (f16*)(W + 63700992 + 4718592);
    f16*  Hh    = (f16*)(W + 63700992 + 9437184);
    f16*  meanx = (f16*)(W + 63700992);
    f16*  stdx  = (f16*)(W + 63700992 + 4718592);
    f16*  conth = (f16*)(W + 63700992 + 9437184);
    f16*  xh    = (f16*)(W + 63700992);
    float* w_a  = (float*)(W + 77856768);
    float* w_b  = (float*)(W + 77856768 + 9216);
    float* lrs  = (float*)(W + 77856768 + 18432);
    float* Lnum = (float*)(W + 77856768 + 18440);
    float* Lden = (float*)(W + 77856768 + 18444);
    float* diffArr = (float*)(W + 77856768 + 18448);
    f16*  fwh   = (f16*)(W + 77875712);
    f16*  gwh   = (f16*)(W + 77875712 + 524288);
    f16*  hwh   = (f16*)(W + 77875712 + 1048576);

    init_small<<<1, TPB, 0, stream>>>(w_a, diffArr, Lnum);

    // weight + key conversions
    cvt16<<<256, TPB, 0, stream>>>((const float4*)f_w, (f16x4*)fwh, (long)CDIM * CDIM / 4);
    cvt16<<<256, TPB, 0, stream>>>((const float4*)g_w, (f16x4*)gwh, (long)CDIM * CDIM / 4);
    cvt16<<<256, TPB, 0, stream>>>((const float4*)h_w, (f16x4*)hwh, (long)CDIM * CDIM / 4);
    tcvt<<<dim3(72, 16, 2), TPB, 0, stream>>>(ckey, E16, ckeyT, E16, CDIM, HWD);
    tcvt<<<dim3(72, 16, 2), TPB, 0, stream>>>(skey, E16, skeyT, E16, CDIM, HWD);
    tcvt<<<dim3(72, 16, 2), TPB, 0, stream>>>(style, E16, styleT, E16, CDIM, HWD);

    // convs: Fh[s][c], Gh[s][c] (bias over n=c); Hh[c][s] (bias over m=c)
    sgemm<EPI_F16BIASN><<<dim3(8, 36, 2), TPB, 0, stream>>>(ckeyT, E16, CDIM, fwh, 0, CDIM,
        Fh, E16, CDIM, nullptr, CDIM, f_b, nullptr, nullptr, nullptr, nullptr, 0.f, nullptr, 0);
    sgemm<EPI_F16BIASN><<<dim3(8, 36, 2), TPB, 0, stream>>>(skeyT, E16, CDIM, gwh, 0, CDIM,
        Gh, E16, CDIM, nullptr, CDIM, g_b, nullptr, nullptr, nullptr, nullptr, 0.f, nullptr, 0);
    sgemm<EPI_F16BIASM><<<dim3(36, 8, 2), TPB, 0, stream>>>(hwh, 0, CDIM, styleT, E16, CDIM,
        Hh, E16, HWD, nullptr, CDIM, h_b, nullptr, nullptr, nullptr, nullptr, 0.f, nullptr, 0);

    // logits = Fh . Gh^T -> Sf f32 ; softmax -> Sh f16
    sgemm<EPI_F32><<<dim3(36, 36, 2), TPB, 0, stream>>>(Fh, E16, CDIM, Gh, E16, CDIM,
        Sf, EHH, HWD, nullptr, CDIM, nullptr, nullptr, nullptr, nullptr, nullptr, 0.f, nullptr, 0);
    softmax_h<<<2 * HWD, TPB, 0, stream>>>(Sf, Sh);

    // A conversions (into dead Sf space)
    cvt16<<<2048, TPB, 0, stream>>>((const float4*)Amat, (f16x4*)Ah, EHH / 4);
    tcvt<<<dim3(72, 72, 1), TPB, 0, stream>>>(Amat, 0, At, 0, HWD, HWD);

    // mean/std (dual MFMA), transposed write -> meanx/stdx [b*c][q]
    sgemm<EPI_MEANSTD><<<dim3(8, 36, 2), TPB, 0, stream>>>(Sh, EHH, HWD, Hh, E16, HWD,
        meanx, 0, HWD, stdx, HWD, nullptr, nullptr, nullptr, nullptr, nullptr, 0.f, nullptr, 0);

    cvt16<<<2048, TPB, 0, stream>>>((const float4*)content, (f16x4*)conth, (long)2 * E16 / 4);

    // projections -> f32 [1024][2304]
    sgemm<EPI_F32><<<dim3(36, 16, 1), TPB, 0, stream>>>(meanx, 0, HWD, Ah, 0, HWD,
        meanc, 0, HWD, nullptr, HWD, nullptr, nullptr, nullptr, nullptr, nullptr, 0.f, nullptr, 0);
    sgemm<EPI_F32><<<dim3(36, 16, 1), TPB, 0, stream>>>(stdx, 0, HWD, Ah, 0, HWD,
        stdc, 0, HWD, nullptr, HWD, nullptr, nullptr, nullptr, nullptr, nullptr, 0.f, nullptr, 0);
    sgemm<EPI_F32><<<dim3(36, 16, 1), TPB, 0, stream>>>(conth, 0, HWD, Ah, 0, HWD,
        contc, 0, HWD, nullptr, HWD, nullptr, nullptr, nullptr, nullptr, nullptr, 0.f, nullptr, 0);

    groupnorm_x<<<1024, TPB, 0, stream>>>(contc, meanc, stdc, xh);

    // WtW (f32 + f16), then W2 = Wh^2, W4 = W2^2 (fp16; entries ~lam1^4/2304 ~ 2e3, in range)
    sgemm<EPI_WTW><<<dim3(36, 36, 1), TPB, 0, stream>>>(At, 0, HWD, At, 0, HWD,
        Wf, 0, HWD, Wh, HWD, nullptr, nullptr, nullptr, nullptr, nullptr, 0.f, nullptr, 0);
    sgemm<EPI_F16><<<dim3(36, 36, 1), TPB, 0, stream>>>(Wh, 0, HWD, Wh, 0, HWD,
        W2h, 0, HWD, nullptr, HWD, nullptr, nullptr, nullptr, nullptr, nullptr, 0.f, nullptr, 0);
    sgemm<EPI_F16><<<dim3(36, 36, 1), TPB, 0, stream>>>(W2h, 0, HWD, W2h, 0, HWD,
        W4h, 0, HWD, nullptr, HWD, nullptr, nullptr, nullptr, nullptr, nullptr, 0.f, nullptr, 0);

    // 25 power iterations on W4 == 100 on W (identical Krylov direction); ends in w_b
    for (int it = 0; it < 25; ++it) {
        const float* win = (it & 1) ? w_b : w_a;
        float* wout = (it & 1) ? w_a : w_b;
        matvec_h<<<HWD / 4, TPB, 0, stream>>>(W4h, win, wout);
    }
    kernelL<<<HWD / 4, TPB, 0, stream>>>(Wf, w_b, Lnum, Lden);
    lr_fin<<<1, 1, 0, stream>>>(Lnum, Lden, lrs);

    // xA (loop-invariant) in f16: xAh = xh . At^T  (overwrites dead Wf)
    sgemm<EPI_F16><<<dim3(36, 16, 1), TPB, 0, stream>>>(xh, 0, HWD, At, 0, HWD,
        xAh, 0, HWD, nullptr, HWD, nullptr, nullptr, nullptr, nullptr, nullptr, 0.f, nullptr, 0);

    // z = 0 (f32: 2*E16 floats = 2*E16/4 float4), y = 0 (f16: 2*E16 halves = E16/4 float4)
    zero_kernel<<<1024, TPB, 0, stream>>>((float4*)zf, 2 * E16 / 4);
    zero_kernel<<<1024, TPB, 0, stream>>>((float4*)yh, E16 / 4);

    // FISTA: grad = y@WtW - xA, one fused MFMA GEMM per iteration (y lives in f16 only)
    float t = 1.0f;
    for (int it = 0; it < 43; ++it) {
        const float tn = (1.0f + sqrtf(1.0f + 4.0f * t * t)) * 0.5f;
        const float coef = (t - 1.0f) / tn;
        t = tn;
        sgemm<EPI_FISTA><<<dim3(36, 16, 1), TPB, 0, stream>>>(yh, 0, HWD, Wh, 0, HWD,
            nullptr, 0, HWD, nullptr, HWD, nullptr, xAh, zf, yh, lrs, coef, diffArr, it);
    }

    // out = z (f32: 2*E16 floats = 2*E16/4 float4)
    copy_kernel<<<2048, TPB, 0, stream>>>((const float4*)zf, (float4*)d_out, 2 * E16 / 4);
}